// Round 4
// baseline (371.895 us; speedup 1.0000x reference)
//
#include <hip/hip_runtime.h>
#include <math.h>

// MinGRU: B=8, S=8192, D=256, H=256, fp32 in/out.
// SINGLE fused kernel: block (b,c) = one scan chunk of 64 timesteps.
//   1. bf16-MFMA dual GEMM (z,h) for 64 rows x 256 ch, fragments loaded
//      DIRECT from global (no LDS staging; fp32->bf16 via v_perm in reg).
//      Each x row is read by exactly one block -> x fetched once total.
//   2. sigmoid epilogue -> packed {a=1-z, b=z*h~} bf16 in LDS (never HBM).
//   3. per-16-step segment (P,Q) summaries -> block (P,Q).
//   4. decoupled-lookback over chunk chain (agent-scope acquire/release;
//      chain order == blockIdx order, which matches HW dispatch order).
//   5. replay from LDS, write fp32 h_t to out.
// ws: chunkP/Q/H (3 MB) + flags (4 KB), memset(flags) per launch.

constexpr int B_ = 8;
constexpr int S_ = 8192;
constexpr int D_ = 256;
constexpr int H_ = 256;
constexpr int CHUNKS = 128;
constexpr int CLEN = 64;
constexpr int NBLK = B_ * CHUNKS;  // 1024

typedef __attribute__((ext_vector_type(8))) short bf16x8;
typedef __attribute__((ext_vector_type(4))) float f32x4;

// 2 floats -> 2 bf16 (round-to-nearest-ish) in 2 adds + 1 v_perm.
// lo16 = bf16(f0), hi16 = bf16(f1).
__device__ __forceinline__ uint pack2bf(float f0, float f1) {
  const uint u0 = __float_as_uint(f0) + 0x8000u;
  const uint u1 = __float_as_uint(f1) + 0x8000u;
  return __builtin_amdgcn_perm(u1, u0, 0x07060302u);
}

__device__ __forceinline__ bf16x8 pack8(float4 lo, float4 hi) {
  union { uint4 u; bf16x8 v; } r;
  r.u = make_uint4(pack2bf(lo.x, lo.y), pack2bf(lo.z, lo.w),
                   pack2bf(hi.x, hi.y), pack2bf(hi.z, hi.w));
  return r.v;
}

__device__ __forceinline__ float4 fma4(float4 a, float4 x, float4 b) {
  return make_float4(fmaf(a.x, x.x, b.x), fmaf(a.y, x.y, b.y),
                     fmaf(a.z, x.z, b.z), fmaf(a.w, x.w, b.w));
}
__device__ __forceinline__ float4 mul4(float4 a, float4 b) {
  return make_float4(a.x * b.x, a.y * b.y, a.z * b.z, a.w * b.w);
}

__global__ __launch_bounds__(256, 2) void mingru_mega(
    const float* __restrict__ x, const float* __restrict__ h0,
    const float* __restrict__ whw, const float* __restrict__ whb,
    const float* __restrict__ wzw, const float* __restrict__ wzb,
    float* __restrict__ out,
    float* __restrict__ chunkP, float* __restrict__ chunkQ,
    float* __restrict__ chunkH, uint* __restrict__ flags)
{
  __shared__ uint abt[CLEN][260];      // +4 pad: 2-way-max on epilogue stores
  __shared__ float4 segP[4][64];
  __shared__ float4 segQ[4][64];
  __shared__ float4 hin4[64];

  const int bid = blockIdx.x;
  const int b = bid >> 7;        // sequence
  const int c = bid & 127;       // chunk within sequence (chain position)
  const int tid = threadIdx.x;
  const int w = tid >> 6;        // wave: 64 channels (gemm) / 16 steps (scan)
  const int lane = tid & 63;
  const int cn = lane & 15;
  const int q = lane >> 4;
  const int chw = w * 64;
  const size_t rowbase = (size_t)b * S_ + (size_t)c * CLEN;

  // ------------------------------------------------------------- GEMM ----
  f32x4 accz[4][4] = {};
  f32x4 acch[4][4] = {};

  const float* xp  = x   + (rowbase + cn) * D_ + q * 8;  // +i*16 rows
  const float* wzp = wzw + (size_t)(chw + cn) * D_ + q * 8;
  const float* whp = whw + (size_t)(chw + cn) * D_ + q * 8;

#pragma unroll 2
  for (int kk = 0; kk < D_; kk += 32) {
    bf16x8 af[4];
#pragma unroll
    for (int i = 0; i < 4; i++) {
      const float* p = xp + i * 16 * D_ + kk;
      af[i] = pack8(*(const float4*)p, *(const float4*)(p + 4));
    }
    {
      bf16x8 bz[4];
#pragma unroll
      for (int j = 0; j < 4; j++) {
        const float* p = wzp + j * 16 * D_ + kk;
        bz[j] = pack8(*(const float4*)p, *(const float4*)(p + 4));
      }
#pragma unroll
      for (int i = 0; i < 4; i++)
#pragma unroll
        for (int j = 0; j < 4; j++)
          accz[i][j] = __builtin_amdgcn_mfma_f32_16x16x32_bf16(
              af[i], bz[j], accz[i][j], 0, 0, 0);
    }
    {
      bf16x8 bh[4];
#pragma unroll
      for (int j = 0; j < 4; j++) {
        const float* p = whp + j * 16 * D_ + kk;
        bh[j] = pack8(*(const float4*)p, *(const float4*)(p + 4));
      }
#pragma unroll
      for (int i = 0; i < 4; i++)
#pragma unroll
        for (int j = 0; j < 4; j++)
          acch[i][j] = __builtin_amdgcn_mfma_f32_16x16x32_bf16(
              af[i], bh[j], acch[i][j], 0, 0, 0);
    }
  }

  // Epilogue: C/D layout col=lane&15, row=quad*4+reg. a=e*rcp, b=hpre*rcp.
#pragma unroll
  for (int j = 0; j < 4; j++) {
    const int ch = chw + j * 16 + cn;
    const float zb = wzb[ch], hb = whb[ch];
#pragma unroll
    for (int i = 0; i < 4; i++) {
#pragma unroll
      for (int r = 0; r < 4; r++) {
        const int row = i * 16 + q * 4 + r;
        const float zpre = accz[i][j][r] + zb;
        const float hpre = acch[i][j][r] + hb;
        const float e = __expf(-zpre);
        const float rcp = __builtin_amdgcn_rcpf(1.0f + e);  // z = rcp
        abt[row][ch] = pack2bf(e * rcp, hpre * rcp);        // {a, b}
      }
    }
  }
  __syncthreads();

  // -------------------------------------------- segment (P,Q) summaries --
  // wave w owns steps w*16..w*16+15; lane owns channels lane*4..+3.
  {
    float4 P = make_float4(1.f, 1.f, 1.f, 1.f);
    float4 Q = make_float4(0.f, 0.f, 0.f, 0.f);
#pragma unroll
    for (int t = 0; t < 16; t++) {
      const uint4 v = *(const uint4*)&abt[w * 16 + t][lane * 4];
      const float4 a = make_float4(__uint_as_float(v.x << 16), __uint_as_float(v.y << 16),
                                   __uint_as_float(v.z << 16), __uint_as_float(v.w << 16));
      const float4 bb = make_float4(__uint_as_float(v.x & 0xFFFF0000u), __uint_as_float(v.y & 0xFFFF0000u),
                                    __uint_as_float(v.z & 0xFFFF0000u), __uint_as_float(v.w & 0xFFFF0000u));
      Q = fma4(a, Q, bb);
      P = mul4(P, a);
    }
    segP[w][lane] = P;
    segQ[w][lane] = Q;
  }
  __syncthreads();

  // ------------------------------------- block (P,Q), publish, lookback --
  if (tid < 64) {
    float4 Pb = segP[0][lane], Qb = segQ[0][lane];
#pragma unroll
    for (int s = 1; s < 4; s++) {
      const float4 Ps = segP[s][lane], Qs = segQ[s][lane];
      Qb = fma4(Ps, Qb, Qs);
      Pb = mul4(Pb, Ps);
    }
    const size_t cb = (size_t)bid * H_ + lane * 4;
    float4 hinv;
    if (c == 0) {
      hinv = *(const float4*)(h0 + (size_t)b * H_ + lane * 4);
    } else {
      *(float4*)(chunkP + cb) = Pb;
      *(float4*)(chunkQ + cb) = Qb;
      __hip_atomic_store(&flags[bid], 1u, __ATOMIC_RELEASE,
                         __HIP_MEMORY_SCOPE_AGENT);
      float4 Pa = make_float4(1.f, 1.f, 1.f, 1.f);
      float4 Qa = make_float4(0.f, 0.f, 0.f, 0.f);
      int j = c - 1;
      for (;;) {
        const uint f = __hip_atomic_load(&flags[b * CHUNKS + j],
                                         __ATOMIC_ACQUIRE,
                                         __HIP_MEMORY_SCOPE_AGENT);
        if (__all(f >= 2u)) {   // inclusive state available
          const float4 Hj = *(const float4*)(chunkH + (size_t)(b * CHUNKS + j) * H_ + lane * 4);
          hinv = fma4(Pa, Hj, Qa);
          break;
        } else if (__all(f >= 1u)) {  // aggregate: compose, step back
          const float4 Pj = *(const float4*)(chunkP + (size_t)(b * CHUNKS + j) * H_ + lane * 4);
          const float4 Qj = *(const float4*)(chunkQ + (size_t)(b * CHUNKS + j) * H_ + lane * 4);
          Qa = fma4(Pa, Qj, Qa);
          Pa = mul4(Pa, Pj);
          --j;
        } else {
          __builtin_amdgcn_s_sleep(4);
        }
      }
    }
    // publish inclusive ASAP, then share h_in with the block
    *(float4*)(chunkH + cb) = fma4(Pb, hinv, Qb);
    __hip_atomic_store(&flags[bid], 2u, __ATOMIC_RELEASE,
                       __HIP_MEMORY_SCOPE_AGENT);
    hin4[lane] = hinv;
  }
  __syncthreads();

  // ------------------------------------------------------------ replay ---
  {
    float4 st = hin4[lane];
#pragma unroll
    for (int s = 0; s < 3; s++)  // compose segments below my wave
      if (s < w) {
        st = fma4(segP[s][lane], st, segQ[s][lane]);
      }
    float* op = out + (rowbase + w * 16) * H_ + lane * 4;
#pragma unroll
    for (int t = 0; t < 16; t++) {
      const uint4 v = *(const uint4*)&abt[w * 16 + t][lane * 4];
      const float4 a = make_float4(__uint_as_float(v.x << 16), __uint_as_float(v.y << 16),
                                   __uint_as_float(v.z << 16), __uint_as_float(v.w << 16));
      const float4 bb = make_float4(__uint_as_float(v.x & 0xFFFF0000u), __uint_as_float(v.y & 0xFFFF0000u),
                                    __uint_as_float(v.z & 0xFFFF0000u), __uint_as_float(v.w & 0xFFFF0000u));
      st = fma4(a, st, bb);
      *(float4*)(op + (size_t)t * H_) = st;
    }
  }
}

extern "C" void kernel_launch(void* const* d_in, const int* in_sizes, int n_in,
                              void* d_out, int out_size, void* d_ws, size_t ws_size,
                              hipStream_t stream) {
  const float* x   = (const float*)d_in[0];
  const float* h0  = (const float*)d_in[1];
  const float* whw = (const float*)d_in[2];
  const float* whb = (const float*)d_in[3];
  const float* wzw = (const float*)d_in[4];
  const float* wzb = (const float*)d_in[5];
  float* out = (float*)d_out;

  float* chunkP = (float*)d_ws;                       // [NBLK,H]
  float* chunkQ = chunkP + (size_t)NBLK * H_;         // [NBLK,H]
  float* chunkH = chunkQ + (size_t)NBLK * H_;         // [NBLK,H]
  uint*  flags  = (uint*)(chunkH + (size_t)NBLK * H_);// [NBLK]

  hipMemsetAsync(flags, 0, NBLK * sizeof(uint), stream);
  mingru_mega<<<NBLK, 256, 0, stream>>>(x, h0, whw, whb, wzw, wzb, out,
                                        chunkP, chunkQ, chunkH, flags);
}

// Round 5
// 191.089 us; speedup vs baseline: 1.9462x; 1.9462x over previous
//
#include <hip/hip_runtime.h>
#include <math.h>

// MinGRU: B=8, S=8192, D=256, H=256, fp32 in/out.
//   K1 gemm_zh : bf16-MFMA dual GEMM (z,h) + sigmoid epilogue.
//                fp32->bf16 via v_perm (1.5 ops/elem). Writes packed
//                {a=1-z lo16, b=z*h~ hi16} bf16 -> ws. No fused phase-A
//                (R3 showed LDS round-trip fusion is a net loss).
//   K2 phaseA  : per-chunk (P,Q); 1 block/chunk, 1 ch/thread, batch-8.
//   K3 phaseB  : sequential scan over chunk summaries (batch-8).
//   K4 phaseC  : replay; 1 block/chunk, 1 ch/thread, batch-8, fp32 out.
// No cross-block chaining (R4: lookback hop = ~2.2 us through LLC).

constexpr int B_ = 8;
constexpr int S_ = 8192;
constexpr int D_ = 256;
constexpr int H_ = 256;
constexpr int M_ = B_ * S_;        // 65536 rows
constexpr int CHUNKS = 128;
constexpr int CLEN = S_ / CHUNKS;  // 64

typedef __attribute__((ext_vector_type(8))) short bf16x8;
typedef __attribute__((ext_vector_type(4))) float f32x4;

// 2 floats -> 2 bf16 (round-to-nearest, ties-away): 2 adds + 1 v_perm.
// lo16 = bf16(f0), hi16 = bf16(f1).
__device__ __forceinline__ uint pack2bf(float f0, float f1) {
  const uint u0 = __float_as_uint(f0) + 0x8000u;
  const uint u1 = __float_as_uint(f1) + 0x8000u;
  return __builtin_amdgcn_perm(u1, u0, 0x07060302u);
}

// ---------------------------------------------------------------- GEMM ----
// Block: 256 thr = 4 waves. Tile: 128 rows x 64 h-channels, both projections.
// LDS rows padded to 72 bf16: conflict-free b128 fragment reads.
__global__ __launch_bounds__(256) void gemm_zh(
    const float* __restrict__ x,
    const float* __restrict__ whw, const float* __restrict__ whb,
    const float* __restrict__ wzw, const float* __restrict__ wzb,
    uint* __restrict__ ab)
{
  __shared__ ushort xs[128][72];
  __shared__ ushort wzs[64][72];
  __shared__ ushort whs[64][72];

  const int tid = threadIdx.x;
  // XCD swizzle: one 128-row x-panel per XCD group -> x L2-local.
  const int g    = blockIdx.x;
  const int xcd  = g & 7;
  const int loc  = g >> 3;
  const int nt   = loc & 3;
  const int panel = (loc >> 2) * 8 + xcd;
  const int m0 = panel * 128;
  const int n0 = nt * 64;

  const int lane = tid & 63;
  const int w  = tid >> 6;
  const int mb = (w & 1) * 64;
  const int nb = (w >> 1) * 32;
  const int q  = lane >> 4;
  const int cn = lane & 15;

  f32x4 accz[4][2] = {};
  f32x4 acch[4][2] = {};

  for (int k0 = 0; k0 < D_; k0 += 64) {
    __syncthreads();  // WAR guard on LDS reuse
#pragma unroll
    for (int f = 0; f < 8; f++) {  // x: 128 rows x 64 k
      const int idx = tid + 256 * f;
      const int row = idx >> 4, seg = idx & 15;
      float4 v = *(const float4*)(x + (size_t)(m0 + row) * D_ + k0 + seg * 4);
      *(uint2*)&xs[row][seg * 4] =
          make_uint2(pack2bf(v.x, v.y), pack2bf(v.z, v.w));
    }
#pragma unroll
    for (int f = 0; f < 4; f++) {  // weights: 64 rows x 64 k each
      const int idx = tid + 256 * f;
      const int row = idx >> 4, seg = idx & 15;
      float4 vz = *(const float4*)(wzw + (size_t)(n0 + row) * D_ + k0 + seg * 4);
      float4 vh = *(const float4*)(whw + (size_t)(n0 + row) * D_ + k0 + seg * 4);
      *(uint2*)&wzs[row][seg * 4] =
          make_uint2(pack2bf(vz.x, vz.y), pack2bf(vz.z, vz.w));
      *(uint2*)&whs[row][seg * 4] =
          make_uint2(pack2bf(vh.x, vh.y), pack2bf(vh.z, vh.w));
    }
    __syncthreads();
#pragma unroll
    for (int ks = 0; ks < 2; ks++) {
      const int kk = ks * 32 + q * 8;  // A[m=lane&15][k=quad*8+j]
      bf16x8 af[4], bz[2], bh[2];
#pragma unroll
      for (int i = 0; i < 4; i++)
        af[i] = *(const bf16x8*)&xs[mb + i * 16 + cn][kk];
#pragma unroll
      for (int j = 0; j < 2; j++) {
        bz[j] = *(const bf16x8*)&wzs[nb + j * 16 + cn][kk];
        bh[j] = *(const bf16x8*)&whs[nb + j * 16 + cn][kk];
      }
#pragma unroll
      for (int i = 0; i < 4; i++)
#pragma unroll
        for (int j = 0; j < 2; j++) {
          accz[i][j] = __builtin_amdgcn_mfma_f32_16x16x32_bf16(af[i], bz[j], accz[i][j], 0, 0, 0);
          acch[i][j] = __builtin_amdgcn_mfma_f32_16x16x32_bf16(af[i], bh[j], acch[i][j], 0, 0, 0);
        }
    }
  }

  // Epilogue: C/D col=lane&15, row=quad*4+reg. a=e*rcp, b=h~*rcp.
#pragma unroll
  for (int j = 0; j < 2; j++) {
    const int ch = n0 + nb + j * 16 + cn;
    const float zb = wzb[ch], hb = whb[ch];
#pragma unroll
    for (int i = 0; i < 4; i++) {
#pragma unroll
      for (int r = 0; r < 4; r++) {
        const int row = m0 + mb + i * 16 + q * 4 + r;
        const float zpre = accz[i][j][r] + zb;
        const float hpre = acch[i][j][r] + hb;
        const float e = __expf(-zpre);
        const float rcp = __builtin_amdgcn_rcpf(1.0f + e);  // z
        ab[(size_t)row * H_ + ch] = pack2bf(e * rcp, hpre * rcp);
      }
    }
  }
}

// ---------------------------------------------------------------- scans ---
// Phase A: chunk (P,Q). Block = (chunk, b); thread = 1 channel; batch-8.
__global__ __launch_bounds__(256) void scan_phaseA(
    const uint* __restrict__ ab,
    float* __restrict__ P_out, float* __restrict__ Q_out)
{
  const int c = blockIdx.x;
  const int b = blockIdx.y;
  const int ch = threadIdx.x;
  size_t base = ((size_t)b * S_ + (size_t)c * CLEN) * H_ + ch;
  float P = 1.f, Q = 0.f;
  for (int t0 = 0; t0 < CLEN; t0 += 8) {
    uint v[8];
#pragma unroll
    for (int j = 0; j < 8; j++)
      v[j] = ab[base + (size_t)(t0 + j) * H_];
#pragma unroll
    for (int j = 0; j < 8; j++) {
      const float a = __uint_as_float(v[j] << 16);
      const float bb = __uint_as_float(v[j] & 0xFFFF0000u);
      Q = fmaf(a, Q, bb);
      P *= a;
    }
  }
  const size_t idx = ((size_t)b * CHUNKS + c) * H_ + ch;
  P_out[idx] = P;
  Q_out[idx] = Q;
}

// Phase B: sequential scan over chunk summaries, batch-8.
__global__ __launch_bounds__(256) void scan_phaseB(
    const float* __restrict__ h0in, const float* __restrict__ P,
    const float* __restrict__ Q, float* __restrict__ hstate)
{
  const int b = blockIdx.x;
  const int h = threadIdx.x;
  const size_t base = (size_t)b * CHUNKS * H_ + h;
  float hc = h0in[(size_t)b * H_ + h];
  for (int c0 = 0; c0 < CHUNKS; c0 += 8) {
    float p[8], q[8];
#pragma unroll
    for (int j = 0; j < 8; j++) {
      p[j] = P[base + (size_t)(c0 + j) * H_];
      q[j] = Q[base + (size_t)(c0 + j) * H_];
    }
#pragma unroll
    for (int j = 0; j < 8; j++) {
      hstate[base + (size_t)(c0 + j) * H_] = hc;
      hc = fmaf(p[j], hc, q[j]);
    }
  }
}

// Phase C: replay. Block = (chunk, b); thread = 1 channel; batch-8.
__global__ __launch_bounds__(256) void scan_phaseC(
    const uint* __restrict__ ab, const float* __restrict__ hstate,
    float* __restrict__ out)
{
  const int c = blockIdx.x;
  const int b = blockIdx.y;
  const int ch = threadIdx.x;
  size_t base = ((size_t)b * S_ + (size_t)c * CLEN) * H_ + ch;
  float hc = hstate[((size_t)b * CHUNKS + c) * H_ + ch];
  for (int t0 = 0; t0 < CLEN; t0 += 8) {
    uint v[8];
#pragma unroll
    for (int j = 0; j < 8; j++)
      v[j] = ab[base + (size_t)(t0 + j) * H_];
#pragma unroll
    for (int j = 0; j < 8; j++) {
      const float a = __uint_as_float(v[j] << 16);
      const float bb = __uint_as_float(v[j] & 0xFFFF0000u);
      hc = fmaf(a, hc, bb);
      out[base + (size_t)(t0 + j) * H_] = hc;
    }
  }
}

extern "C" void kernel_launch(void* const* d_in, const int* in_sizes, int n_in,
                              void* d_out, int out_size, void* d_ws, size_t ws_size,
                              hipStream_t stream) {
  const float* x   = (const float*)d_in[0];
  const float* h0  = (const float*)d_in[1];
  const float* whw = (const float*)d_in[2];
  const float* whb = (const float*)d_in[3];
  const float* wzw = (const float*)d_in[4];
  const float* wzb = (const float*)d_in[5];
  float* out = (float*)d_out;

  uint*  ab     = (uint*)d_ws;                        // [M,H] packed bf16 {b,a}
  float* chunkP = (float*)(ab + (size_t)M_ * H_);     // [B,CHUNKS,H]
  float* chunkQ = chunkP + (size_t)B_ * CHUNKS * H_;  // [B,CHUNKS,H]
  float* hstate = chunkQ + (size_t)B_ * CHUNKS * H_;  // [B,CHUNKS,H]

  gemm_zh<<<(M_ / 128) * 4, 256, 0, stream>>>(x, whw, whb, wzw, wzb, ab);
  scan_phaseA<<<dim3(CHUNKS, B_), 256, 0, stream>>>(ab, chunkP, chunkQ);
  scan_phaseB<<<B_, 256, 0, stream>>>(h0, chunkP, chunkQ, hstate);
  scan_phaseC<<<dim3(CHUNKS, B_), 256, 0, stream>>>(ab, hstate, out);
}